// Round 1
// 2030.809 us; speedup vs baseline: 1.9233x; 1.9233x over previous
//
#include <hip/hip_runtime.h>
#include <cmath>

// PolicyStep: B=4 T=2048 V=8192 D=512 NOPS=8 HID=1024 POL_OUT=1032
// Round 3: move all GEMMs to MFMA (bf16 hi/lo split, 3-term emulated fp32).
//   - mfma_f32_16x16x32_bf16, 128x128 tile, BK=32, 4 waves x (64x64, 4x4 frags)
//   - reg-staged global->split->LDS (conversion forbids global_load_lds)
//   - LDS [128][40] ushort: 80B row stride -> ~2-way bank aliasing (free)
//   - next K-tile global loads issued before MFMA section (latency overlap)
//   - V stored transposed so every GEMM is B^T layout (contiguous along K)

namespace {

constexpr int Bb = 4, Tt = 2048, Vv = 8192, Dd = 512, HID = 1024, PO = 1032;
constexpr int NTOK = Bb * Tt; // 8192

typedef short bf16x8 __attribute__((ext_vector_type(8)));
typedef float f32x4 __attribute__((ext_vector_type(4)));

enum { EPI_STORE = 0, EPI_DECAY = 1, EPI_ACCUM = 2, EPI_BIAS_GELU = 3,
       EPI_BIAS = 4, EPI_OUT = 5, EPI_STORE_VT = 6 };

__device__ __forceinline__ ushort bf16_rn(float a) {
  union { float f; unsigned u; } c; c.f = a;
  return (ushort)((c.u + 0x7FFFu + ((c.u >> 16) & 1u)) >> 16);
}

// a ~= hi + lo with |err| ~ 2^-17 |a|
__device__ __forceinline__ void split2(float a, ushort& hi, ushort& lo) {
  const ushort h = bf16_rn(a);
  union { unsigned u; float f; } hf; hf.u = ((unsigned)h) << 16;
  hi = h;
  lo = bf16_rn(a - hf.f);
}

// C[M,N] = epilogue( sum_k A[m,k] * B[n,k] )   (B always row-per-output-col)
// emulated fp32: acc += Ahi*Bhi + Alo*Bhi + Ahi*Blo
template <int EPI, bool SKIPK, bool NGUARD>
__launch_bounds__(256)
__global__ void gemm_mfma(int M, int N, int K,
                          const float* __restrict__ A, int lda, long long sAz,
                          const float* __restrict__ B, int ldb, long long sBz,
                          float* __restrict__ C, int ldc, long long sCz,
                          const float* __restrict__ rowScale,
                          const float* __restrict__ bias,
                          const float* __restrict__ scale_ptr,
                          const float* __restrict__ decayPow) {
  const int bx = blockIdx.x, by = blockIdx.y, bz = blockIdx.z;
  if (EPI == EPI_DECAY) {
    if (bx < by) return; // whole tile j<i => w==0, never read downstream
  }
  __shared__ ushort AsH[128][40], AsL[128][40], BsH[128][40], BsL[128][40];
  A += (long long)bz * sAz;
  B += (long long)bz * sBz;
  const int tid = threadIdx.x;
  const int sr = tid >> 1;          // staged row 0..127
  const int sc = (tid & 1) * 16;    // staged col 0 or 16
  const int arow = by * 128 + sr;
  const int brow = bx * 128 + sr;
  const float ascale = rowScale ? rowScale[arow] : 1.0f;
  const bool bok = !NGUARD || (brow < N);
  const int w = tid >> 6, lane = tid & 63;
  const int wr = (w >> 1) * 64, wc = (w & 1) * 64;
  const int r16 = lane & 15, kg = lane >> 4;

  f32x4 acc[4][4];
#pragma unroll
  for (int i = 0; i < 4; ++i)
#pragma unroll
    for (int j = 0; j < 4; ++j) acc[i][j] = (f32x4)0.0f;

  const int k0 = SKIPK ? by * 128 : 0; // mem GEMM: k<by*128 rows of scores are 0

  float4 ra[4], rb[4];
  auto load_tiles = [&](int kt) {
    const float* Ap = A + (long long)arow * lda + kt + sc;
#pragma unroll
    for (int u = 0; u < 4; ++u) ra[u] = *reinterpret_cast<const float4*>(Ap + 4 * u);
    if (bok) {
      const float* Bp = B + (long long)brow * ldb + kt + sc;
#pragma unroll
      for (int u = 0; u < 4; ++u) rb[u] = *reinterpret_cast<const float4*>(Bp + 4 * u);
    } else {
#pragma unroll
      for (int u = 0; u < 4; ++u) rb[u] = make_float4(0.f, 0.f, 0.f, 0.f);
    }
  };

  load_tiles(k0);
  for (int kt = k0; kt < K; kt += 32) {
    // convert + stage current tile
#pragma unroll
    for (int u = 0; u < 4; ++u) {
      ushort4 h4, l4;
      split2(ra[u].x * ascale, h4.x, l4.x);
      split2(ra[u].y * ascale, h4.y, l4.y);
      split2(ra[u].z * ascale, h4.z, l4.z);
      split2(ra[u].w * ascale, h4.w, l4.w);
      *reinterpret_cast<ushort4*>(&AsH[sr][sc + 4 * u]) = h4;
      *reinterpret_cast<ushort4*>(&AsL[sr][sc + 4 * u]) = l4;
      split2(rb[u].x, h4.x, l4.x);
      split2(rb[u].y, h4.y, l4.y);
      split2(rb[u].z, h4.z, l4.z);
      split2(rb[u].w, h4.w, l4.w);
      *reinterpret_cast<ushort4*>(&BsH[sr][sc + 4 * u]) = h4;
      *reinterpret_cast<ushort4*>(&BsL[sr][sc + 4 * u]) = l4;
    }
    __syncthreads();
    if (kt + 32 < K) load_tiles(kt + 32); // overlap next-tile HBM with MFMA

    bf16x8 aH[4], aL[4];
#pragma unroll
    for (int fi = 0; fi < 4; ++fi) {
      aH[fi] = *reinterpret_cast<const bf16x8*>(&AsH[wr + fi * 16 + r16][kg * 8]);
      aL[fi] = *reinterpret_cast<const bf16x8*>(&AsL[wr + fi * 16 + r16][kg * 8]);
    }
#pragma unroll
    for (int fj = 0; fj < 4; ++fj) {
      const bf16x8 bH = *reinterpret_cast<const bf16x8*>(&BsH[wc + fj * 16 + r16][kg * 8]);
      const bf16x8 bL = *reinterpret_cast<const bf16x8*>(&BsL[wc + fj * 16 + r16][kg * 8]);
#pragma unroll
      for (int fi = 0; fi < 4; ++fi) {
        acc[fi][fj] = __builtin_amdgcn_mfma_f32_16x16x32_bf16(aH[fi], bH, acc[fi][fj], 0, 0, 0);
        acc[fi][fj] = __builtin_amdgcn_mfma_f32_16x16x32_bf16(aL[fi], bH, acc[fi][fj], 0, 0, 0);
        acc[fi][fj] = __builtin_amdgcn_mfma_f32_16x16x32_bf16(aH[fi], bL, acc[fi][fj], 0, 0, 0);
      }
    }
    __syncthreads();
  }

  float scl = 1.0f;
  if (EPI == EPI_ACCUM || EPI == EPI_OUT) scl = *scale_ptr;
#pragma unroll
  for (int fi = 0; fi < 4; ++fi) {
    const int row = by * 128 + wr + fi * 16 + kg * 4;
#pragma unroll
    for (int fj = 0; fj < 4; ++fj) {
      const int col = bx * 128 + wc + fj * 16 + r16;
      if (NGUARD && col >= N) continue;
#pragma unroll
      for (int rg = 0; rg < 4; ++rg) {
        const int r = row + rg;
        const float v = acc[fi][fj][rg];
        if (EPI == EPI_STORE) {
          C[(long long)bz * sCz + (long long)r * ldc + col] = v;
        } else if (EPI == EPI_STORE_VT) {
          // vT[batch][d][t]: batch = r/T, t = r%T
          C[(long long)(r >> 11) * ((long long)Dd * Tt) + (long long)col * Tt + (r & 2047)] = v;
        } else if (EPI == EPI_DECAY) {
          const int d = col - r;
          C[(long long)bz * sCz + (long long)r * ldc + col] =
              (d > 0) ? v * decayPow[d - 1] : 0.0f;
        } else if (EPI == EPI_ACCUM) {
          C[(long long)bz * sCz + (long long)r * ldc + col] += scl * v;
        } else if (EPI == EPI_BIAS_GELU) {
          const float t = v + bias[col];
          C[(long long)r * ldc + col] = 0.5f * t * (1.0f + erff(t * 0.70710678118654752440f));
        } else if (EPI == EPI_BIAS) {
          C[(long long)r * ldc + col] = v + bias[col];
        } else { // EPI_OUT
          C[(long long)r * ldc + col] = v * scl;
        }
      }
    }
  }
}

__global__ void decaypow_kernel(const float* __restrict__ decay_logit,
                                float* __restrict__ pw) {
  const int e = blockIdx.x * 256 + threadIdx.x;
  if (e < Tt) {
    const float decay = 1.0f / (1.0f + expf(-*decay_logit));
    pw[e] = powf(decay, (float)e);
  }
}

__global__ void rmsnorm_kernel(const float* __restrict__ x,
                               float* __restrict__ rstd) {
  const int t = blockIdx.x, tid = threadIdx.x;
  const float4* xr = reinterpret_cast<const float4*>(x + (long long)t * Vv);
  float s = 0.0f;
  for (int i = tid; i < Vv / 4; i += 256) {
    const float4 v = xr[i];
    s += v.x * v.x + v.y * v.y + v.z * v.z + v.w * v.w;
  }
  __shared__ float red[256];
  red[tid] = s;
  __syncthreads();
  for (int st = 128; st > 0; st >>= 1) {
    if (tid < st) red[tid] += red[tid + st];
    __syncthreads();
  }
  if (tid == 0) rstd[t] = rsqrtf(red[0] / (float)Vv + 1.1920929e-07f);
}

// per-token: read_w=softmax(pol[:512]) -> sel=h*read_w; op_w=softmax(pol[512:520]);
// write_w=sigmoid(pol[520:]) in place.
__global__ void policy_kernel(float* __restrict__ pol, const float* __restrict__ h,
                              float* __restrict__ sel, float* __restrict__ opw) {
  const int t = blockIdx.x, tid = threadIdx.x;
  float* prow = pol + (long long)t * PO;
  __shared__ float red[256];
  const float v0 = prow[tid], v1 = prow[tid + 256];
  red[tid] = fmaxf(v0, v1);
  __syncthreads();
  for (int s = 128; s > 0; s >>= 1) {
    if (tid < s) red[tid] = fmaxf(red[tid], red[tid + s]);
    __syncthreads();
  }
  const float mx = red[0];
  __syncthreads();
  const float e0 = expf(v0 - mx), e1 = expf(v1 - mx);
  red[tid] = e0 + e1;
  __syncthreads();
  for (int s = 128; s > 0; s >>= 1) {
    if (tid < s) red[tid] += red[tid + s];
    __syncthreads();
  }
  const float inv = 1.0f / red[0];
  const float* hrow = h + (long long)t * Dd;
  sel[(long long)t * Dd + tid] = hrow[tid] * e0 * inv;
  sel[(long long)t * Dd + tid + 256] = hrow[tid + 256] * e1 * inv;
  if (tid == 0) {
    float ov[8];
    float om = -1e30f;
    for (int n = 0; n < 8; ++n) { ov[n] = prow[512 + n]; om = fmaxf(om, ov[n]); }
    float osum = 0.0f;
    for (int n = 0; n < 8; ++n) { ov[n] = expf(ov[n] - om); osum += ov[n]; }
    const float oi = 1.0f / osum;
    for (int n = 0; n < 8; ++n) opw[(long long)t * 8 + n] = ov[n] * oi;
  }
  const float w0 = prow[520 + tid];
  prow[520 + tid] = 1.0f / (1.0f + expf(-w0));
  const float w1 = prow[520 + 256 + tid];
  prow[520 + 256 + tid] = 1.0f / (1.0f + expf(-w1));
}

// result[t,e] = write_w[t,e] * sum_n opw[t,n] * act_n( sum_d sel[t,d]*Wops[n,e,d] )
__launch_bounds__(256)
__global__ void opbank_mfma(const float* __restrict__ sel,
                            const float* __restrict__ Wops,
                            const float* __restrict__ opw,
                            const float* __restrict__ pol,
                            float* __restrict__ result) {
  const int bx = blockIdx.x, by = blockIdx.y;
  __shared__ ushort AsH[128][40], AsL[128][40], BsH[128][40], BsL[128][40];
  const int tid = threadIdx.x;
  const int sr = tid >> 1, sc = (tid & 1) * 16;
  const int arow = by * 128 + sr, brow = bx * 128 + sr;
  const int w = tid >> 6, lane = tid & 63;
  const int wr = (w >> 1) * 64, wc = (w & 1) * 64;
  const int r16 = lane & 15, kg = lane >> 4;

  f32x4 res[4][4];
#pragma unroll
  for (int i = 0; i < 4; ++i)
#pragma unroll
    for (int j = 0; j < 4; ++j) res[i][j] = (f32x4)0.0f;

  for (int n = 0; n < 8; ++n) {
    const float* Bn = Wops + (long long)n * Dd * Dd;
    f32x4 acc[4][4];
#pragma unroll
    for (int i = 0; i < 4; ++i)
#pragma unroll
      for (int j = 0; j < 4; ++j) acc[i][j] = (f32x4)0.0f;

    for (int kt = 0; kt < Dd; kt += 32) {
#pragma unroll
      for (int u = 0; u < 4; ++u) {
        const float4 av = *reinterpret_cast<const float4*>(
            sel + (long long)arow * Dd + kt + sc + 4 * u);
        ushort4 h4, l4;
        split2(av.x, h4.x, l4.x); split2(av.y, h4.y, l4.y);
        split2(av.z, h4.z, l4.z); split2(av.w, h4.w, l4.w);
        *reinterpret_cast<ushort4*>(&AsH[sr][sc + 4 * u]) = h4;
        *reinterpret_cast<ushort4*>(&AsL[sr][sc + 4 * u]) = l4;
        const float4 bv = *reinterpret_cast<const float4*>(
            Bn + (long long)brow * Dd + kt + sc + 4 * u);
        split2(bv.x, h4.x, l4.x); split2(bv.y, h4.y, l4.y);
        split2(bv.z, h4.z, l4.z); split2(bv.w, h4.w, l4.w);
        *reinterpret_cast<ushort4*>(&BsH[sr][sc + 4 * u]) = h4;
        *reinterpret_cast<ushort4*>(&BsL[sr][sc + 4 * u]) = l4;
      }
      __syncthreads();
      bf16x8 aH[4], aL[4];
#pragma unroll
      for (int fi = 0; fi < 4; ++fi) {
        aH[fi] = *reinterpret_cast<const bf16x8*>(&AsH[wr + fi * 16 + r16][kg * 8]);
        aL[fi] = *reinterpret_cast<const bf16x8*>(&AsL[wr + fi * 16 + r16][kg * 8]);
      }
#pragma unroll
      for (int fj = 0; fj < 4; ++fj) {
        const bf16x8 bH = *reinterpret_cast<const bf16x8*>(&BsH[wc + fj * 16 + r16][kg * 8]);
        const bf16x8 bL = *reinterpret_cast<const bf16x8*>(&BsL[wc + fj * 16 + r16][kg * 8]);
#pragma unroll
        for (int fi = 0; fi < 4; ++fi) {
          acc[fi][fj] = __builtin_amdgcn_mfma_f32_16x16x32_bf16(aH[fi], bH, acc[fi][fj], 0, 0, 0);
          acc[fi][fj] = __builtin_amdgcn_mfma_f32_16x16x32_bf16(aL[fi], bH, acc[fi][fj], 0, 0, 0);
          acc[fi][fj] = __builtin_amdgcn_mfma_f32_16x16x32_bf16(aH[fi], bL, acc[fi][fj], 0, 0, 0);
        }
      }
      __syncthreads();
    }
    // fold op n into res with activation + op weight (n is block-uniform)
#pragma unroll
    for (int fi = 0; fi < 4; ++fi) {
#pragma unroll
      for (int rg = 0; rg < 4; ++rg) {
        const int r = by * 128 + wr + fi * 16 + kg * 4 + rg;
        const float ow = opw[(long long)r * 8 + n];
#pragma unroll
        for (int fj = 0; fj < 4; ++fj) {
          const float hv = acc[fi][fj][rg];
          float av;
          switch (n) {
            case 0: av = 0.5f * hv * (1.0f + erff(hv * 0.70710678118654752440f)); break;
            case 1: av = fmaxf(hv, 0.0f); break;
            case 2: { const float r_ = fmaxf(hv, 0.0f); av = r_ * r_; } break;
            case 3: av = hv / (1.0f + expf(-hv)); break;
            case 4: av = tanhf(hv); break;
            case 5: av = 1.0f / (1.0f + expf(-hv)); break;
            case 6: av = hv; break;
            default: av = -hv; break;
          }
          res[fi][fj][rg] += ow * av;
        }
      }
    }
  }
#pragma unroll
  for (int fi = 0; fi < 4; ++fi) {
#pragma unroll
    for (int fj = 0; fj < 4; ++fj) {
      const int col = bx * 128 + wc + fj * 16 + r16;
#pragma unroll
      for (int rg = 0; rg < 4; ++rg) {
        const int r = by * 128 + wr + fi * 16 + kg * 4 + rg;
        const float ww = pol[(long long)r * PO + 520 + col];
        result[(long long)r * Dd + col] = res[fi][fj][rg] * ww;
      }
    }
  }
}

} // namespace

extern "C" void kernel_launch(void* const* d_in, const int* in_sizes, int n_in,
                              void* d_out, int out_size, void* d_ws, size_t ws_size,
                              hipStream_t stream) {
  const float* x    = (const float*)d_in[0];
  const float* Wc   = (const float*)d_in[1];
  const float* We   = (const float*)d_in[2];
  const float* Wq   = (const float*)d_in[3];
  const float* Wk   = (const float*)d_in[4];
  const float* Wv   = (const float*)d_in[5];
  const float* W1   = (const float*)d_in[6];
  const float* b1   = (const float*)d_in[7];
  const float* W2   = (const float*)d_in[8];
  const float* b2   = (const float*)d_in[9];
  const float* Wops = (const float*)d_in[10];
  const float* dlg  = (const float*)d_in[11];
  const float* msc  = (const float*)d_in[12];
  const float* asc  = (const float*)d_in[13];

  float* ws = (float*)d_ws;
  // lifetime-aliased layout (~135 MB):
  float* h      = ws;                         // 4,194,304
  float* q      = ws + 4194304;               // dead after scores -> sel
  float* k      = ws + 2 * 4194304;           // dead after scores -> result
  float* vT     = ws + 3 * 4194304;           // v transposed per batch [D][T]; dead after mem
  float* scores = ws + 4 * 4194304;           // 16,777,216; dead after mem
  float* a1     = scores;                     // 8,388,608 (reuse scores)
  float* pol    = scores + 8388608;           // 8,454,144
  float* sel    = q;                          // 4,194,304 (reuse q)
  float* result = k;                          // 4,194,304 (reuse k)
  float* rstd   = pol + 8454144;              // 8192
  float* dpw    = rstd + 8192;                // 2048
  float* opw    = dpw + 2048;                 // 65,536
  float* out    = (float*)d_out;

  decaypow_kernel<<<8, 256, 0, stream>>>(dlg, dpw);
  rmsnorm_kernel<<<NTOK, 256, 0, stream>>>(x, rstd);

  // h = (x * rstd) @ Wc^T   [8192 x 512 x 8192]
  gemm_mfma<EPI_STORE, false, false>
      <<<dim3(4, 64, 1), 256, 0, stream>>>(NTOK, Dd, Vv, x, Vv, 0, Wc, Vv, 0,
                                           h, Dd, 0, rstd, nullptr, nullptr, nullptr);
  // q,k = h @ W{q,k}^T  [8192 x 512 x 512]
  gemm_mfma<EPI_STORE, false, false>
      <<<dim3(4, 64, 1), 256, 0, stream>>>(NTOK, Dd, Dd, h, Dd, 0, Wq, Dd, 0,
                                           q, Dd, 0, nullptr, nullptr, nullptr, nullptr);
  gemm_mfma<EPI_STORE, false, false>
      <<<dim3(4, 64, 1), 256, 0, stream>>>(NTOK, Dd, Dd, h, Dd, 0, Wk, Dd, 0,
                                           k, Dd, 0, nullptr, nullptr, nullptr, nullptr);
  // vT[b][d][t] = (h @ Wv^T)^T  -> makes mem GEMM's B-operand K-contiguous
  gemm_mfma<EPI_STORE_VT, false, false>
      <<<dim3(4, 64, 1), 256, 0, stream>>>(NTOK, Dd, Dd, h, Dd, 0, Wv, Dd, 0,
                                           vT, Tt, 0, nullptr, nullptr, nullptr, nullptr);
  // scores = (q @ k^T) * w  [per batch 2048 x 2048 x 512], lower-tri tiles skipped
  gemm_mfma<EPI_DECAY, false, false>
      <<<dim3(16, 16, 4), 256, 0, stream>>>(Tt, Tt, Dd, q, Dd, (long long)Tt * Dd,
                                            k, Dd, (long long)Tt * Dd,
                                            scores, Tt, (long long)Tt * Tt,
                                            nullptr, nullptr, nullptr, dpw);
  // h += mem_scale * (scores @ v)  [per batch 2048 x 512 x 2048], zero k-tiles skipped
  gemm_mfma<EPI_ACCUM, true, false>
      <<<dim3(4, 16, 4), 256, 0, stream>>>(Tt, Dd, Tt, scores, Tt, (long long)Tt * Tt,
                                           vT, Tt, (long long)Dd * Tt,
                                           h, Dd, (long long)Tt * Dd,
                                           nullptr, nullptr, msc, nullptr);
  // a1 = gelu(h @ W1^T + b1)  [8192 x 1024 x 512]
  gemm_mfma<EPI_BIAS_GELU, false, false>
      <<<dim3(8, 64, 1), 256, 0, stream>>>(NTOK, HID, Dd, h, Dd, 0, W1, Dd, 0,
                                           a1, HID, 0, nullptr, b1, nullptr, nullptr);
  // pol = a1 @ W2^T + b2  [8192 x 1032 x 1024]
  gemm_mfma<EPI_BIAS, false, true>
      <<<dim3(9, 64, 1), 256, 0, stream>>>(NTOK, PO, HID, a1, HID, 0, W2, HID, 0,
                                           pol, PO, 0, nullptr, b2, nullptr, nullptr);
  policy_kernel<<<NTOK, 256, 0, stream>>>(pol, h, sel, opw);
  opbank_mfma<<<dim3(4, 64, 1), 256, 0, stream>>>(sel, Wops, opw, pol, result);
  // out = (result @ We^T) * act_scale  [8192 x 8192 x 512]
  gemm_mfma<EPI_OUT, false, false>
      <<<dim3(64, 64, 1), 256, 0, stream>>>(NTOK, Vv, Dd, result, Dd, 0, We, Dd, 0,
                                            out, Vv, 0, nullptr, nullptr, asc, nullptr);
}

// Round 2
// 1679.839 us; speedup vs baseline: 2.3252x; 1.2089x over previous
//
#include <hip/hip_runtime.h>
#include <cmath>

// PolicyStep: B=4 T=2048 V=8192 D=512 NOPS=8 HID=1024 POL_OUT=1032
// Round 4: occupancy + staging-VALU fix.
//   - all GEMM operands carried as pre-split bf16 hi/lo PLANES (4 B/elem, same
//     footprint as f32): weights split once up-front; intermediate GEMM outputs
//     written as planes in the epilogue. Staging = pure ushort8 copies.
//   - 128x64 tile, 4 waves x (64x32), BK=32 -> every grid >= 512 blocks;
//     __launch_bounds__(256,3) -> 3 blocks/CU.
//   - opbank split over z=2 (4 ops each) -> 1024 blocks; f32 partials into dead
//     h/vT regions; combine kernel applies write_w and emits result planes.
//   - bijective XCD swizzle (m204) on all GEMM grids.
//   - workspace layout identical 134.8 MB envelope via lifetime aliasing.

namespace {

constexpr int Tt = 2048, Vv = 8192, Dd = 512, HID = 1024, PO = 1032;
constexpr int NTOK = 8192;

typedef unsigned short u16;
typedef u16 u16x4 __attribute__((ext_vector_type(4)));
typedef u16 u16x8 __attribute__((ext_vector_type(8)));
typedef short bf16x8 __attribute__((ext_vector_type(8)));
typedef float f32x4 __attribute__((ext_vector_type(4)));

enum { EPI_STORE_F32 = 0, EPI_STORE_P, EPI_VT_P, EPI_DECAY_P, EPI_ACCUM,
       EPI_GELU_P, EPI_BIAS_F32, EPI_OUT };

__device__ __forceinline__ u16 bf16_rn(float a) {
  union { float f; unsigned u; } c; c.f = a;
  return (u16)((c.u + 0x7FFFu + ((c.u >> 16) & 1u)) >> 16);
}
// a ~= hi + lo with |err| ~ 2^-17 |a|
__device__ __forceinline__ void split2(float a, u16& hi, u16& lo) {
  const u16 h = bf16_rn(a);
  union { unsigned u; float f; } hf; hf.u = ((unsigned)h) << 16;
  hi = h; lo = bf16_rn(a - hf.f);
}
// bijective XCD-chunk swizzle (m204)
__device__ __forceinline__ int swz(int flat, int nwg) {
  const int xcd = flat & 7, pos = flat >> 3;
  const int q8 = nwg >> 3, r8 = nwg & 7;
  return (xcd < r8 ? xcd * (q8 + 1) : r8 * (q8 + 1) + (xcd - r8) * q8) + pos;
}

// C[M,N] = epilogue( sum_k A[m,k] * B[n,k] ), emulated fp32 via 3-term bf16.
// A: f32 (AF32, split on stage, optional rowScale) or hi/lo planes.
// B: always hi/lo planes. Tile 128x64, BK=32, 4 waves of 64x32.
template <int EPI, bool AF32, bool SKIPK, bool NGUARD>
__launch_bounds__(256, 3)
__global__ void gemm_mfma(int gridX, int N, int K,
                          const void* __restrict__ Aptr, int lda, long long sAz, long long aPlane,
                          const u16* __restrict__ Bptr, int ldb, long long sBz, long long bPlane,
                          void* __restrict__ Cptr, int ldc, long long sCz, long long cPlane,
                          const float* __restrict__ rowScale,
                          const float* __restrict__ bias,
                          const float* __restrict__ scale_ptr,
                          const float* __restrict__ decayPow) {
  const int flat = swz(blockIdx.x, gridDim.x);
  const int bx = flat % gridX, by = flat / gridX, bz = blockIdx.z;
  if (EPI == EPI_DECAY_P && bx * 64 + 63 <= by * 128) return; // all j<=i: w==0, never read

  __shared__ u16 AsH[128][40], AsL[128][40], BsH[64][40], BsL[64][40];
  const int tid = threadIdx.x;
  const int sr = tid >> 1, sc = (tid & 1) << 4;   // A stage: 2 thr/row, 16 cols each
  const int br = tid >> 2, bc = (tid & 3) << 3;   // B stage: 4 thr/row, 8 cols each
  const int arow = by * 128 + sr;
  const int brow = bx * 64 + br;
  const bool bok = !NGUARD || (brow < N);
  const int w = tid >> 6, lane = tid & 63;
  const int wr = (w >> 1) << 6, wc = (w & 1) << 5; // wave tile 64x32
  const int r16 = lane & 15, kg = lane >> 4;

  float ascale = 1.0f;
  if (AF32 && rowScale) ascale = rowScale[arow];

  f32x4 acc[4][2];
#pragma unroll
  for (int i = 0; i < 4; ++i)
#pragma unroll
    for (int j = 0; j < 2; ++j) acc[i][j] = (f32x4)0.0f;

  const int k0 = SKIPK ? by * 128 : 0; // mem GEMM: scores cols < by*128 are zero

  float4 raf[4];
  u16x8 rah[2], ral[2], rbh, rbl;

  auto load_tiles = [&](int kt) {
    if constexpr (AF32) {
      const float* Aq = (const float*)Aptr + (long long)bz * sAz + (long long)arow * lda + kt + sc;
#pragma unroll
      for (int u = 0; u < 4; ++u) raf[u] = *reinterpret_cast<const float4*>(Aq + 4 * u);
    } else {
      const u16* Aq = (const u16*)Aptr + (long long)bz * sAz + (long long)arow * lda + kt + sc;
      rah[0] = *reinterpret_cast<const u16x8*>(Aq);
      rah[1] = *reinterpret_cast<const u16x8*>(Aq + 8);
      ral[0] = *reinterpret_cast<const u16x8*>(Aq + aPlane);
      ral[1] = *reinterpret_cast<const u16x8*>(Aq + aPlane + 8);
    }
    if (bok) {
      const u16* Bq = Bptr + (long long)bz * sBz + (long long)brow * ldb + kt + bc;
      rbh = *reinterpret_cast<const u16x8*>(Bq);
      rbl = *reinterpret_cast<const u16x8*>(Bq + bPlane);
    } else {
      rbh = (u16x8)0; rbl = (u16x8)0;
    }
  };

  auto stage = [&]() {
    if constexpr (AF32) {
#pragma unroll
      for (int u = 0; u < 4; ++u) {
        u16 h0, h1, h2, h3, l0, l1, l2, l3;
        split2(raf[u].x * ascale, h0, l0);
        split2(raf[u].y * ascale, h1, l1);
        split2(raf[u].z * ascale, h2, l2);
        split2(raf[u].w * ascale, h3, l3);
        u16x4 hv = {h0, h1, h2, h3}, lv = {l0, l1, l2, l3};
        *reinterpret_cast<u16x4*>(&AsH[sr][sc + 4 * u]) = hv;
        *reinterpret_cast<u16x4*>(&AsL[sr][sc + 4 * u]) = lv;
      }
    } else {
      *reinterpret_cast<u16x8*>(&AsH[sr][sc]) = rah[0];
      *reinterpret_cast<u16x8*>(&AsH[sr][sc + 8]) = rah[1];
      *reinterpret_cast<u16x8*>(&AsL[sr][sc]) = ral[0];
      *reinterpret_cast<u16x8*>(&AsL[sr][sc + 8]) = ral[1];
    }
    *reinterpret_cast<u16x8*>(&BsH[br][bc]) = rbh;
    *reinterpret_cast<u16x8*>(&BsL[br][bc]) = rbl;
  };

  load_tiles(k0);
  for (int kt = k0; kt < K; kt += 32) {
    stage();
    __syncthreads();
    if (kt + 32 < K) load_tiles(kt + 32); // overlap next HBM fetch with MFMA
    bf16x8 aH[4], aL[4];
#pragma unroll
    for (int fi = 0; fi < 4; ++fi) {
      aH[fi] = *reinterpret_cast<const bf16x8*>(&AsH[wr + fi * 16 + r16][kg * 8]);
      aL[fi] = *reinterpret_cast<const bf16x8*>(&AsL[wr + fi * 16 + r16][kg * 8]);
    }
#pragma unroll
    for (int fj = 0; fj < 2; ++fj) {
      const bf16x8 bH = *reinterpret_cast<const bf16x8*>(&BsH[wc + fj * 16 + r16][kg * 8]);
      const bf16x8 bL = *reinterpret_cast<const bf16x8*>(&BsL[wc + fj * 16 + r16][kg * 8]);
#pragma unroll
      for (int fi = 0; fi < 4; ++fi) {
        acc[fi][fj] = __builtin_amdgcn_mfma_f32_16x16x32_bf16(aH[fi], bH, acc[fi][fj], 0, 0, 0);
        acc[fi][fj] = __builtin_amdgcn_mfma_f32_16x16x32_bf16(aL[fi], bH, acc[fi][fj], 0, 0, 0);
        acc[fi][fj] = __builtin_amdgcn_mfma_f32_16x16x32_bf16(aH[fi], bL, acc[fi][fj], 0, 0, 0);
      }
    }
    __syncthreads();
  }

  float scl = 1.0f;
  if (EPI == EPI_ACCUM || EPI == EPI_OUT) scl = *scale_ptr;
#pragma unroll
  for (int fi = 0; fi < 4; ++fi) {
    const int row = by * 128 + wr + fi * 16 + kg * 4;
#pragma unroll
    for (int fj = 0; fj < 2; ++fj) {
      const int col = bx * 64 + wc + fj * 16 + r16;
      if (NGUARD && col >= N) continue;
#pragma unroll
      for (int rg = 0; rg < 4; ++rg) {
        const int r = row + rg;
        float v = acc[fi][fj][rg];
        if constexpr (EPI == EPI_STORE_F32) {
          ((float*)Cptr)[(long long)bz * sCz + (long long)r * ldc + col] = v;
        } else if constexpr (EPI == EPI_STORE_P) {
          u16 hh, ll; split2(v, hh, ll);
          u16* Cp = (u16*)Cptr;
          const long long idx = (long long)bz * sCz + (long long)r * ldc + col;
          Cp[idx] = hh; Cp[idx + cPlane] = ll;
        } else if constexpr (EPI == EPI_VT_P) {
          const long long idx = (long long)(r >> 11) * ((long long)Dd * Tt) +
                                (long long)col * Tt + (r & 2047);
          u16 hh, ll; split2(v, hh, ll);
          u16* Cp = (u16*)Cptr;
          Cp[idx] = hh; Cp[idx + cPlane] = ll;
        } else if constexpr (EPI == EPI_DECAY_P) {
          const int d = col - r;
          v = (d > 0) ? v * decayPow[d - 1] : 0.0f;
          u16 hh, ll; split2(v, hh, ll);
          u16* Cp = (u16*)Cptr;
          const long long idx = (long long)bz * sCz + (long long)r * ldc + col;
          Cp[idx] = hh; Cp[idx + cPlane] = ll;
        } else if constexpr (EPI == EPI_ACCUM) {
          ((float*)Cptr)[(long long)bz * sCz + (long long)r * ldc + col] += scl * v;
        } else if constexpr (EPI == EPI_GELU_P) {
          const float t = v + bias[col];
          const float g = 0.5f * t * (1.0f + erff(t * 0.70710678118654752440f));
          u16 hh, ll; split2(g, hh, ll);
          u16* Cp = (u16*)Cptr;
          const long long idx = (long long)r * ldc + col;
          Cp[idx] = hh; Cp[idx + cPlane] = ll;
        } else if constexpr (EPI == EPI_BIAS_F32) {
          ((float*)Cptr)[(long long)r * ldc + col] = v + bias[col];
        } else { // EPI_OUT
          ((float*)Cptr)[(long long)r * ldc + col] = v * scl;
        }
      }
    }
  }
}

// opbank: per z (2), 4 ops; partial[r,e] = sum_n opw[r,n]*act_n(sel@Wops[n]^T)
__launch_bounds__(256, 2)
__global__ void opbank_mfma(int gridX,
                            const u16* __restrict__ selP, long long aPlane,
                            const u16* __restrict__ WopsP, long long bPlane,
                            const float* __restrict__ opw,
                            float* __restrict__ part0, float* __restrict__ part1) {
  const int flat = swz(blockIdx.x, gridDim.x);
  const int bx = flat % gridX, by = flat / gridX, bz = blockIdx.z;
  float* __restrict__ part = (bz == 0) ? part0 : part1;

  __shared__ u16 AsH[128][40], AsL[128][40], BsH[64][40], BsL[64][40];
  const int tid = threadIdx.x;
  const int sr = tid >> 1, sc = (tid & 1) << 4;
  const int br = tid >> 2, bc = (tid & 3) << 3;
  const int arow = by * 128 + sr;
  const int brow = bx * 64 + br;
  const int w = tid >> 6, lane = tid & 63;
  const int wr = (w >> 1) << 6, wc = (w & 1) << 5;
  const int r16 = lane & 15, kg = lane >> 4;

  f32x4 res[4][2];
#pragma unroll
  for (int i = 0; i < 4; ++i)
#pragma unroll
    for (int j = 0; j < 2; ++j) res[i][j] = (f32x4)0.0f;

  u16x8 rah[2], ral[2], rbh, rbl;

  for (int nn = 0; nn < 4; ++nn) {
    const int n = bz * 4 + nn;
    const u16* Bn = WopsP + (long long)n * (Dd * Dd);
    f32x4 acc[4][2];
#pragma unroll
    for (int i = 0; i < 4; ++i)
#pragma unroll
      for (int j = 0; j < 2; ++j) acc[i][j] = (f32x4)0.0f;

    auto load_tiles = [&](int kt) {
      const u16* Aq = selP + (long long)arow * Dd + kt + sc;
      rah[0] = *reinterpret_cast<const u16x8*>(Aq);
      rah[1] = *reinterpret_cast<const u16x8*>(Aq + 8);
      ral[0] = *reinterpret_cast<const u16x8*>(Aq + aPlane);
      ral[1] = *reinterpret_cast<const u16x8*>(Aq + aPlane + 8);
      const u16* Bq = Bn + (long long)brow * Dd + kt + bc;
      rbh = *reinterpret_cast<const u16x8*>(Bq);
      rbl = *reinterpret_cast<const u16x8*>(Bq + bPlane);
    };
    load_tiles(0);
    for (int kt = 0; kt < Dd; kt += 32) {
      *reinterpret_cast<u16x8*>(&AsH[sr][sc]) = rah[0];
      *reinterpret_cast<u16x8*>(&AsH[sr][sc + 8]) = rah[1];
      *reinterpret_cast<u16x8*>(&AsL[sr][sc]) = ral[0];
      *reinterpret_cast<u16x8*>(&AsL[sr][sc + 8]) = ral[1];
      *reinterpret_cast<u16x8*>(&BsH[br][bc]) = rbh;
      *reinterpret_cast<u16x8*>(&BsL[br][bc]) = rbl;
      __syncthreads();
      if (kt + 32 < Dd) load_tiles(kt + 32);
      bf16x8 aH[4], aL[4];
#pragma unroll
      for (int fi = 0; fi < 4; ++fi) {
        aH[fi] = *reinterpret_cast<const bf16x8*>(&AsH[wr + fi * 16 + r16][kg * 8]);
        aL[fi] = *reinterpret_cast<const bf16x8*>(&AsL[wr + fi * 16 + r16][kg * 8]);
      }
#pragma unroll
      for (int fj = 0; fj < 2; ++fj) {
        const bf16x8 bH = *reinterpret_cast<const bf16x8*>(&BsH[wc + fj * 16 + r16][kg * 8]);
        const bf16x8 bL = *reinterpret_cast<const bf16x8*>(&BsL[wc + fj * 16 + r16][kg * 8]);
#pragma unroll
        for (int fi = 0; fi < 4; ++fi) {
          acc[fi][fj] = __builtin_amdgcn_mfma_f32_16x16x32_bf16(aH[fi], bH, acc[fi][fj], 0, 0, 0);
          acc[fi][fj] = __builtin_amdgcn_mfma_f32_16x16x32_bf16(aL[fi], bH, acc[fi][fj], 0, 0, 0);
          acc[fi][fj] = __builtin_amdgcn_mfma_f32_16x16x32_bf16(aH[fi], bL, acc[fi][fj], 0, 0, 0);
        }
      }
      __syncthreads();
    }
#pragma unroll
    for (int fi = 0; fi < 4; ++fi) {
#pragma unroll
      for (int rg = 0; rg < 4; ++rg) {
        const int r = by * 128 + wr + fi * 16 + kg * 4 + rg;
        const float ow = opw[(long long)r * 8 + n];
#pragma unroll
        for (int fj = 0; fj < 2; ++fj) {
          const float hv = acc[fi][fj][rg];
          float av;
          switch (n) {
            case 0: av = 0.5f * hv * (1.0f + erff(hv * 0.70710678118654752440f)); break;
            case 1: av = fmaxf(hv, 0.0f); break;
            case 2: { const float r_ = fmaxf(hv, 0.0f); av = r_ * r_; } break;
            case 3: av = hv / (1.0f + expf(-hv)); break;
            case 4: av = tanhf(hv); break;
            case 5: av = 1.0f / (1.0f + expf(-hv)); break;
            case 6: av = hv; break;
            default: av = -hv; break;
          }
          res[fi][fj][rg] += ow * av;
        }
      }
    }
  }
#pragma unroll
  for (int fi = 0; fi < 4; ++fi)
#pragma unroll
    for (int fj = 0; fj < 2; ++fj) {
      const int col = bx * 64 + wc + fj * 16 + r16;
#pragma unroll
      for (int rg = 0; rg < 4; ++rg) {
        const int r = by * 128 + wr + fi * 16 + kg * 4 + rg;
        part[(long long)r * Dd + col] = res[fi][fj][rg];
      }
    }
}

__global__ void decaypow_kernel(const float* __restrict__ decay_logit,
                                float* __restrict__ pw) {
  const int e = blockIdx.x * 256 + threadIdx.x;
  if (e < Tt) {
    const float decay = 1.0f / (1.0f + expf(-*decay_logit));
    pw[e] = powf(decay, (float)e);
  }
}

__global__ void rmsnorm_kernel(const float* __restrict__ x,
                               float* __restrict__ rstd) {
  const int t = blockIdx.x, tid = threadIdx.x;
  const float4* xr = reinterpret_cast<const float4*>(x + (long long)t * Vv);
  float s = 0.0f;
  for (int i = tid; i < Vv / 4; i += 256) {
    const float4 v = xr[i];
    s += v.x * v.x + v.y * v.y + v.z * v.z + v.w * v.w;
  }
  __shared__ float red[256];
  red[tid] = s;
  __syncthreads();
  for (int st = 128; st > 0; st >>= 1) {
    if (tid < st) red[tid] += red[tid + st];
    __syncthreads();
  }
  if (tid == 0) rstd[t] = rsqrtf(red[0] / (float)Vv + 1.1920929e-07f);
}

// split src f32 -> dst planes {hi[n], lo[n]}
__global__ void split_kernel(const float* __restrict__ src, u16* __restrict__ dst,
                             long long n) {
  const long long i0 = ((long long)blockIdx.x * 256 + threadIdx.x) * 4;
  const long long stride = (long long)gridDim.x * 1024;
  for (long long i = i0; i < n; i += stride) {
    const float4 v = *reinterpret_cast<const float4*>(src + i);
    u16 hh, ll; u16x4 hv, lv;
    split2(v.x, hh, ll); hv[0] = hh; lv[0] = ll;
    split2(v.y, hh, ll); hv[1] = hh; lv[1] = ll;
    split2(v.z, hh, ll); hv[2] = hh; lv[2] = ll;
    split2(v.w, hh, ll); hv[3] = hh; lv[3] = ll;
    *reinterpret_cast<u16x4*>(&dst[i]) = hv;
    *reinterpret_cast<u16x4*>(&dst[n + i]) = lv;
  }
}

// per-token: read_w softmax -> selP planes; op_w softmax; write_w sigmoid in place
__global__ void policy_kernel(float* __restrict__ pol, const float* __restrict__ h,
                              u16* __restrict__ selP, float* __restrict__ opw) {
  const int t = blockIdx.x, tid = threadIdx.x;
  float* prow = pol + (long long)t * PO;
  __shared__ float red[256];
  const float v0 = prow[tid], v1 = prow[tid + 256];
  red[tid] = fmaxf(v0, v1);
  __syncthreads();
  for (int s = 128; s > 0; s >>= 1) {
    if (tid < s) red[tid] = fmaxf(red[tid], red[tid + s]);
    __syncthreads();
  }
  const float mx = red[0];
  __syncthreads();
  const float e0 = expf(v0 - mx), e1 = expf(v1 - mx);
  red[tid] = e0 + e1;
  __syncthreads();
  for (int s = 128; s > 0; s >>= 1) {
    if (tid < s) red[tid] += red[tid + s];
    __syncthreads();
  }
  const float inv = 1.0f / red[0];
  const float* hrow = h + (long long)t * Dd;
  u16 hh, ll;
  const float s0 = hrow[tid] * e0 * inv;
  split2(s0, hh, ll);
  selP[(long long)t * Dd + tid] = hh;
  selP[(long long)t * Dd + tid + 4194304] = ll;
  const float s1 = hrow[tid + 256] * e1 * inv;
  split2(s1, hh, ll);
  selP[(long long)t * Dd + tid + 256] = hh;
  selP[(long long)t * Dd + tid + 256 + 4194304] = ll;
  if (tid == 0) {
    float ov[8];
    float om = -1e30f;
    for (int n = 0; n < 8; ++n) { ov[n] = prow[512 + n]; om = fmaxf(om, ov[n]); }
    float osum = 0.0f;
    for (int n = 0; n < 8; ++n) { ov[n] = expf(ov[n] - om); osum += ov[n]; }
    const float oi = 1.0f / osum;
    for (int n = 0; n < 8; ++n) opw[(long long)t * 8 + n] = ov[n] * oi;
  }
  const float w0 = prow[520 + tid];
  prow[520 + tid] = 1.0f / (1.0f + expf(-w0));
  const float w1 = prow[520 + 256 + tid];
  prow[520 + 256 + tid] = 1.0f / (1.0f + expf(-w1));
}

// result planes = write_w * (p0 + p1)
__global__ void combine_kernel(const float* __restrict__ p0, const float* __restrict__ p1,
                               const float* __restrict__ pol, u16* __restrict__ resP) {
  const long long total = (long long)NTOK * Dd;
  const long long i0 = ((long long)blockIdx.x * 256 + threadIdx.x) * 4;
  const long long stride = (long long)gridDim.x * 1024;
  for (long long i = i0; i < total; i += stride) {
    const float4 a = *reinterpret_cast<const float4*>(p0 + i);
    const float4 b = *reinterpret_cast<const float4*>(p1 + i);
    const long long t = i >> 9;
    const int e = (int)(i & 511);
    const float4 wv = *reinterpret_cast<const float4*>(pol + t * PO + 520 + e);
    u16 hh, ll; u16x4 hv, lv;
    split2((a.x + b.x) * wv.x, hh, ll); hv[0] = hh; lv[0] = ll;
    split2((a.y + b.y) * wv.y, hh, ll); hv[1] = hh; lv[1] = ll;
    split2((a.z + b.z) * wv.z, hh, ll); hv[2] = hh; lv[2] = ll;
    split2((a.w + b.w) * wv.w, hh, ll); hv[3] = hh; lv[3] = ll;
    *reinterpret_cast<u16x4*>(&resP[i]) = hv;
    *reinterpret_cast<u16x4*>(&resP[i + 4194304]) = lv;
  }
}

} // namespace

extern "C" void kernel_launch(void* const* d_in, const int* in_sizes, int n_in,
                              void* d_out, int out_size, void* d_ws, size_t ws_size,
                              hipStream_t stream) {
  const float* x    = (const float*)d_in[0];
  const float* Wc   = (const float*)d_in[1];
  const float* We   = (const float*)d_in[2];
  const float* Wq   = (const float*)d_in[3];
  const float* Wk   = (const float*)d_in[4];
  const float* Wv   = (const float*)d_in[5];
  const float* W1   = (const float*)d_in[6];
  const float* b1   = (const float*)d_in[7];
  const float* W2   = (const float*)d_in[8];
  const float* b2   = (const float*)d_in[9];
  const float* Wops = (const float*)d_in[10];
  const float* dlg  = (const float*)d_in[11];
  const float* msc  = (const float*)d_in[12];
  const float* asc  = (const float*)d_in[13];

  float* ws = (float*)d_ws;
  // ---- lifetime-aliased layout, 134.8 MB total (same envelope as round 3) ----
  float* h    = ws;                           // [0, 4.19M) f32; then p0
  u16*   qkP  = (u16*)(ws + 4194304);         // qP planes; kP at +8388608 u16;
                                              //   later selP (q region), WeP (q region)
  u16*   vTP  = (u16*)(ws + 12582912);        // vT planes; later W2P, then p1
  u16*   scP  = (u16*)(ws + 16777216);        // scores planes [16.78M elems];
                                              //   early WcP/WqP; later a1P/WopsP
  float* pol  = ws + 25165824;                // 8,454,144 f32 (early: W1P)
  float* rstd = ws + 33619968;                // 8192
  float* dpw  = rstd + 8192;                  // 2048
  float* opw  = dpw + 2048;                   // 65,536
  float* out  = (float*)d_out;

  u16*   WcP   = scP;                         // 4,194,304 elems; dead after h GEMM
  u16*   WqP   = (u16*)(ws + 20971520);       // Wq/Wk/Wv packs (524,288 u16 apart)
  u16*   W1P   = (u16*)(ws + 25165824);       // pol region; overwritten by W2 GEMM
  u16*   W2P   = (u16*)(ws + 12582912);       // vT region (vT dead after mem)
  u16*   WopsP = (u16*)(ws + 16777216);       // scores region (a1 dead after W2)
  u16*   a1P   = (u16*)(ws + 16777216);       // after mem, until W2
  u16*   selP  = qkP;                         // after policy (q dead)
  u16*   resP  = (u16*)(ws + 8388608);        // k region (k dead after scores)
  u16*   WeP   = qkP;                         // after opbank (sel dead)
  float* p0    = h;                           // h dead after policy
  float* p1    = ws + 12582912;               // vT/W2P region, dead by opbank

  decaypow_kernel<<<8, 256, 0, stream>>>(dlg, dpw);
  rmsnorm_kernel<<<NTOK, 256, 0, stream>>>(x, rstd);
  split_kernel<<<2048, 256, 0, stream>>>(Wc, WcP, 4194304LL);
  split_kernel<<<256, 256, 0, stream>>>(Wq, WqP, 262144LL);
  split_kernel<<<256, 256, 0, stream>>>(Wk, WqP + 524288, 262144LL);
  split_kernel<<<256, 256, 0, stream>>>(Wv, WqP + 1048576, 262144LL);

  // h = (x*rstd) @ Wc^T  [8192 x 512 x 8192]
  gemm_mfma<EPI_STORE_F32, true, false, false><<<dim3(512, 1, 1), 256, 0, stream>>>(
      8, Dd, Vv, x, Vv, 0, 0, WcP, Vv, 0, 4194304, h, Dd, 0, 0,
      rstd, nullptr, nullptr, nullptr);
  // q,k = h @ W{q,k}^T  fused over z  [8192 x 512 x 512]
  gemm_mfma<EPI_STORE_P, true, false, false><<<dim3(512, 1, 2), 256, 0, stream>>>(
      8, Dd, Dd, h, Dd, 0, 0, WqP, Dd, 524288, 262144, qkP, Dd, 8388608, 4194304,
      nullptr, nullptr, nullptr, nullptr);
  // vT[b][d][t] = (h @ Wv^T)^T
  gemm_mfma<EPI_VT_P, true, false, false><<<dim3(512, 1, 1), 256, 0, stream>>>(
      8, Dd, Dd, h, Dd, 0, 0, WqP + 1048576, Dd, 0, 262144, vTP, 0, 0, 4194304,
      nullptr, nullptr, nullptr, nullptr);
  // scores = (q @ k^T) * w  [per batch 2048 x 2048 x 512], lower-tri tiles skipped
  gemm_mfma<EPI_DECAY_P, false, false, false><<<dim3(512, 1, 4), 256, 0, stream>>>(
      32, Tt, Dd, qkP, Dd, 1048576, 4194304, qkP + 8388608, Dd, 1048576, 4194304,
      scP, Tt, 4194304, 16777216, nullptr, nullptr, nullptr, dpw);
  // h += mem_scale * (scores @ v)  [per batch 2048 x 512 x 2048], zero k skipped
  gemm_mfma<EPI_ACCUM, false, true, false><<<dim3(128, 1, 4), 256, 0, stream>>>(
      8, Dd, Tt, scP, Tt, 4194304, 16777216, vTP, Tt, 1048576, 4194304,
      h, Dd, 1048576, 0, nullptr, nullptr, msc, nullptr);
  split_kernel<<<512, 256, 0, stream>>>(W1, W1P, 524288LL);
  // a1 = gelu(h @ W1^T + b1)  [8192 x 1024 x 512]
  gemm_mfma<EPI_GELU_P, true, false, false><<<dim3(1024, 1, 1), 256, 0, stream>>>(
      16, HID, Dd, h, Dd, 0, 0, W1P, Dd, 0, 524288, a1P, HID, 0, 8388608,
      nullptr, b1, nullptr, nullptr);
  split_kernel<<<1024, 256, 0, stream>>>(W2, W2P, 1056768LL);
  // pol = a1 @ W2^T + b2  [8192 x 1032 x 1024]
  gemm_mfma<EPI_BIAS_F32, false, false, true><<<dim3(1088, 1, 1), 256, 0, stream>>>(
      17, PO, HID, a1P, HID, 0, 8388608, W2P, HID, 0, 1056768, pol, PO, 0, 0,
      nullptr, b2, nullptr, nullptr);
  policy_kernel<<<NTOK, 256, 0, stream>>>(pol, h, selP, opw);
  split_kernel<<<2048, 256, 0, stream>>>(Wops, WopsP, 2097152LL);
  // opbank partials: z=0 -> ops 0..3 into p0, z=1 -> ops 4..7 into p1
  opbank_mfma<<<dim3(512, 1, 2), 256, 0, stream>>>(
      8, selP, 4194304, WopsP, 2097152, opw, p0, p1);
  split_kernel<<<2048, 256, 0, stream>>>(We, WeP, 4194304LL);
  combine_kernel<<<2048, 256, 0, stream>>>(p0, p1, pol, resP);
  // out = (result @ We^T) * act_scale  [8192 x 8192 x 512]
  gemm_mfma<EPI_OUT, false, false, false><<<dim3(8192, 1, 1), 256, 0, stream>>>(
      128, Vv, Dd, resP, Dd, 0, 4194304, WeP, Dd, 0, 4194304, out, Vv, 0, 0,
      nullptr, nullptr, asc, nullptr);
}

// Round 3
// 1574.440 us; speedup vs baseline: 2.4808x; 1.0669x over previous
//
#include <hip/hip_runtime.h>
#include <cmath>

// PolicyStep: B=4 T=2048 V=8192 D=512 NOPS=8 HID=1024 POL_OUT=1032
// Round 5: LDS conflict fix + split-K on the deep GEMM.
//   - chunked LDS layout As[kg][row][8] u16: each 16-lane MFMA fragment read is
//     a contiguous 256B block -> conflict-free (was ~8 excess cyc/b128 read in
//     the [row][40] layout, SQ_LDS_BANK_CONFLICT 5e7).
//   - h GEMM (K=8192) split-K x4 via bz (K=2048 each), partials in dead
//     regions, deterministic combine4. 2048 blocks, launch_bounds(256,4).
//   - operands as bf16 hi/lo planes (3-term emulated fp32 MFMA), as round 4.

namespace {

constexpr int Tt = 2048, Vv = 8192, Dd = 512, HID = 1024, PO = 1032;
constexpr int NTOK = 8192;

typedef unsigned short u16;
typedef u16 u16x4 __attribute__((ext_vector_type(4)));
typedef u16 u16x8 __attribute__((ext_vector_type(8)));
typedef short bf16x8 __attribute__((ext_vector_type(8)));
typedef float f32x4 __attribute__((ext_vector_type(4)));

enum { EPI_STORE_F32 = 0, EPI_STORE_P, EPI_VT_P, EPI_DECAY_P, EPI_ACCUM,
       EPI_GELU_P, EPI_BIAS_F32, EPI_OUT };

__device__ __forceinline__ u16 bf16_rn(float a) {
  union { float f; unsigned u; } c; c.f = a;
  return (u16)((c.u + 0x7FFFu + ((c.u >> 16) & 1u)) >> 16);
}
// a ~= hi + lo with |err| ~ 2^-17 |a|
__device__ __forceinline__ void split2(float a, u16& hi, u16& lo) {
  const u16 h = bf16_rn(a);
  union { unsigned u; float f; } hf; hf.u = ((unsigned)h) << 16;
  hi = h; lo = bf16_rn(a - hf.f);
}
// bijective XCD-chunk swizzle (m204)
__device__ __forceinline__ int swz(int flat, int nwg) {
  const int xcd = flat & 7, pos = flat >> 3;
  const int q8 = nwg >> 3, r8 = nwg & 7;
  return (xcd < r8 ? xcd * (q8 + 1) : r8 * (q8 + 1) + (xcd - r8) * q8) + pos;
}

// C[M,N] = epilogue( sum_k A[m,k] * B[n,k] ), emulated fp32 via 3-term bf16.
// A: f32 (AF32, split on stage, optional rowScale if RS) or hi/lo planes.
// B: always hi/lo planes. Tile 128x64, BK=32, 4 waves of 64x32.
// LDS chunked: As[kg][row][8] -> fragment reads are contiguous 256B/16 lanes.
template <int EPI, bool AF32, bool RS, bool SKIPK, bool NGUARD>
__launch_bounds__(256, 4)
__global__ void gemm_mfma(int gridX, int N, int K,
                          const void* __restrict__ Aptr, int lda, long long sAz, long long aPlane,
                          const u16* __restrict__ Bptr, int ldb, long long sBz, long long bPlane,
                          void* __restrict__ Cptr, int ldc, long long sCz, long long cPlane,
                          const float* __restrict__ rowScale,
                          const float* __restrict__ bias,
                          const float* __restrict__ scale_ptr,
                          const float* __restrict__ decayPow) {
  const int flat = swz(blockIdx.x, gridDim.x);
  const int bx = flat % gridX, by = flat / gridX, bz = blockIdx.z;
  if (EPI == EPI_DECAY_P && bx * 64 + 63 <= by * 128) return; // all j<=i: w==0

  __shared__ u16 AsH[4][128][8], AsL[4][128][8], BsH[4][64][8], BsL[4][64][8];
  const int tid = threadIdx.x;
  const int sr = tid >> 1, ss = tid & 1;          // A stage: 2 thr/row, 16 cols
  const int br = tid >> 2, sbc = tid & 3;         // B stage: 4 thr/row, 8 cols
  const int arow = by * 128 + sr;
  const int brow = bx * 64 + br;
  const bool bok = !NGUARD || (brow < N);
  const int w = tid >> 6, lane = tid & 63;
  const int wr = (w >> 1) << 6, wc = (w & 1) << 5; // wave tile 64x32
  const int r16 = lane & 15, kg = lane >> 4;

  float ascale = 1.0f;
  if (RS) ascale = rowScale[arow];

  f32x4 acc[4][2];
#pragma unroll
  for (int i = 0; i < 4; ++i)
#pragma unroll
    for (int j = 0; j < 2; ++j) acc[i][j] = (f32x4)0.0f;

  const int k0 = SKIPK ? by * 128 : 0; // mem GEMM: scores cols < by*128 are zero

  float4 raf[4];
  u16x8 rah[2], ral[2], rbh, rbl;

  auto load_tiles = [&](int kt) {
    if constexpr (AF32) {
      const float* Aq = (const float*)Aptr + (long long)bz * sAz + (long long)arow * lda + kt + 16 * ss;
#pragma unroll
      for (int u = 0; u < 4; ++u) raf[u] = *reinterpret_cast<const float4*>(Aq + 4 * u);
    } else {
      const u16* Aq = (const u16*)Aptr + (long long)bz * sAz + (long long)arow * lda + kt + 16 * ss;
      rah[0] = *reinterpret_cast<const u16x8*>(Aq);
      rah[1] = *reinterpret_cast<const u16x8*>(Aq + 8);
      ral[0] = *reinterpret_cast<const u16x8*>(Aq + aPlane);
      ral[1] = *reinterpret_cast<const u16x8*>(Aq + aPlane + 8);
    }
    if (bok) {
      const u16* Bq = Bptr + (long long)bz * sBz + (long long)brow * ldb + kt + 8 * sbc;
      rbh = *reinterpret_cast<const u16x8*>(Bq);
      rbl = *reinterpret_cast<const u16x8*>(Bq + bPlane);
    } else {
      rbh = (u16x8)0; rbl = (u16x8)0;
    }
  };

  auto stage = [&]() {
    if constexpr (AF32) {
#pragma unroll
      for (int half = 0; half < 2; ++half) {
        u16x8 hv, lv;
#pragma unroll
        for (int u = 0; u < 2; ++u) {
          const float4 f = raf[half * 2 + u];
          u16 hh, ll;
          float x0 = f.x, x1 = f.y, x2 = f.z, x3 = f.w;
          if (RS) { x0 *= ascale; x1 *= ascale; x2 *= ascale; x3 *= ascale; }
          split2(x0, hh, ll); hv[4 * u + 0] = hh; lv[4 * u + 0] = ll;
          split2(x1, hh, ll); hv[4 * u + 1] = hh; lv[4 * u + 1] = ll;
          split2(x2, hh, ll); hv[4 * u + 2] = hh; lv[4 * u + 2] = ll;
          split2(x3, hh, ll); hv[4 * u + 3] = hh; lv[4 * u + 3] = ll;
        }
        *reinterpret_cast<u16x8*>(&AsH[2 * ss + half][sr][0]) = hv;
        *reinterpret_cast<u16x8*>(&AsL[2 * ss + half][sr][0]) = lv;
      }
    } else {
      *reinterpret_cast<u16x8*>(&AsH[2 * ss][sr][0]) = rah[0];
      *reinterpret_cast<u16x8*>(&AsH[2 * ss + 1][sr][0]) = rah[1];
      *reinterpret_cast<u16x8*>(&AsL[2 * ss][sr][0]) = ral[0];
      *reinterpret_cast<u16x8*>(&AsL[2 * ss + 1][sr][0]) = ral[1];
    }
    *reinterpret_cast<u16x8*>(&BsH[sbc][br][0]) = rbh;
    *reinterpret_cast<u16x8*>(&BsL[sbc][br][0]) = rbl;
  };

  load_tiles(k0);
  for (int kt = k0; kt < K; kt += 32) {
    stage();
    __syncthreads();
    if (kt + 32 < K) load_tiles(kt + 32); // overlap next HBM fetch with MFMA
    bf16x8 aH[4], aL[4];
#pragma unroll
    for (int fi = 0; fi < 4; ++fi) {
      aH[fi] = *reinterpret_cast<const bf16x8*>(&AsH[kg][wr + fi * 16 + r16][0]);
      aL[fi] = *reinterpret_cast<const bf16x8*>(&AsL[kg][wr + fi * 16 + r16][0]);
    }
#pragma unroll
    for (int fj = 0; fj < 2; ++fj) {
      const bf16x8 bH = *reinterpret_cast<const bf16x8*>(&BsH[kg][wc + fj * 16 + r16][0]);
      const bf16x8 bL = *reinterpret_cast<const bf16x8*>(&BsL[kg][wc + fj * 16 + r16][0]);
#pragma unroll
      for (int fi = 0; fi < 4; ++fi) {
        acc[fi][fj] = __builtin_amdgcn_mfma_f32_16x16x32_bf16(aH[fi], bH, acc[fi][fj], 0, 0, 0);
        acc[fi][fj] = __builtin_amdgcn_mfma_f32_16x16x32_bf16(aL[fi], bH, acc[fi][fj], 0, 0, 0);
        acc[fi][fj] = __builtin_amdgcn_mfma_f32_16x16x32_bf16(aH[fi], bL, acc[fi][fj], 0, 0, 0);
      }
    }
    __syncthreads();
  }

  float scl = 1.0f;
  if (EPI == EPI_ACCUM || EPI == EPI_OUT) scl = *scale_ptr;
#pragma unroll
  for (int fi = 0; fi < 4; ++fi) {
    const int row = by * 128 + wr + fi * 16 + kg * 4;
#pragma unroll
    for (int fj = 0; fj < 2; ++fj) {
      const int col = bx * 64 + wc + fj * 16 + r16;
      if (NGUARD && col >= N) continue;
#pragma unroll
      for (int rg = 0; rg < 4; ++rg) {
        const int r = row + rg;
        float v = acc[fi][fj][rg];
        if constexpr (EPI == EPI_STORE_F32) {
          ((float*)Cptr)[(long long)bz * sCz + (long long)r * ldc + col] = v;
        } else if constexpr (EPI == EPI_STORE_P) {
          u16 hh, ll; split2(v, hh, ll);
          u16* Cp = (u16*)Cptr;
          const long long idx = (long long)bz * sCz + (long long)r * ldc + col;
          Cp[idx] = hh; Cp[idx + cPlane] = ll;
        } else if constexpr (EPI == EPI_VT_P) {
          const long long idx = (long long)(r >> 11) * ((long long)Dd * Tt) +
                                (long long)col * Tt + (r & 2047);
          u16 hh, ll; split2(v, hh, ll);
          u16* Cp = (u16*)Cptr;
          Cp[idx] = hh; Cp[idx + cPlane] = ll;
        } else if constexpr (EPI == EPI_DECAY_P) {
          const int d = col - r;
          v = (d > 0) ? v * decayPow[d - 1] : 0.0f;
          u16 hh, ll; split2(v, hh, ll);
          u16* Cp = (u16*)Cptr;
          const long long idx = (long long)bz * sCz + (long long)r * ldc + col;
          Cp[idx] = hh; Cp[idx + cPlane] = ll;
        } else if constexpr (EPI == EPI_ACCUM) {
          ((float*)Cptr)[(long long)bz * sCz + (long long)r * ldc + col] += scl * v;
        } else if constexpr (EPI == EPI_GELU_P) {
          const float t = v + bias[col];
          const float g = 0.5f * t * (1.0f + erff(t * 0.70710678118654752440f));
          u16 hh, ll; split2(g, hh, ll);
          u16* Cp = (u16*)Cptr;
          const long long idx = (long long)r * ldc + col;
          Cp[idx] = hh; Cp[idx + cPlane] = ll;
        } else if constexpr (EPI == EPI_BIAS_F32) {
          ((float*)Cptr)[(long long)r * ldc + col] = v + bias[col];
        } else { // EPI_OUT
          ((float*)Cptr)[(long long)r * ldc + col] = v * scl;
        }
      }
    }
  }
}

// opbank: per z (2), 4 ops; partial[r,e] = sum_n opw[r,n]*act_n(sel@Wops[n]^T)
__launch_bounds__(256, 2)
__global__ void opbank_mfma(int gridX,
                            const u16* __restrict__ selP, long long aPlane,
                            const u16* __restrict__ WopsP, long long bPlane,
                            const float* __restrict__ opw,
                            float* __restrict__ part0, float* __restrict__ part1) {
  const int flat = swz(blockIdx.x, gridDim.x);
  const int bx = flat % gridX, by = flat / gridX, bz = blockIdx.z;
  float* __restrict__ part = (bz == 0) ? part0 : part1;

  __shared__ u16 AsH[4][128][8], AsL[4][128][8], BsH[4][64][8], BsL[4][64][8];
  const int tid = threadIdx.x;
  const int sr = tid >> 1, ss = tid & 1;
  const int br = tid >> 2, sbc = tid & 3;
  const int arow = by * 128 + sr;
  const int brow = bx * 64 + br;
  const int w = tid >> 6, lane = tid & 63;
  const int wr = (w >> 1) << 6, wc = (w & 1) << 5;
  const int r16 = lane & 15, kg = lane >> 4;

  f32x4 res[4][2];
#pragma unroll
  for (int i = 0; i < 4; ++i)
#pragma unroll
    for (int j = 0; j < 2; ++j) res[i][j] = (f32x4)0.0f;

  u16x8 rah[2], ral[2], rbh, rbl;

  for (int nn = 0; nn < 4; ++nn) {
    const int n = bz * 4 + nn;
    const u16* Bn = WopsP + (long long)n * (Dd * Dd);
    f32x4 acc[4][2];
#pragma unroll
    for (int i = 0; i < 4; ++i)
#pragma unroll
      for (int j = 0; j < 2; ++j) acc[i][j] = (f32x4)0.0f;

    auto load_tiles = [&](int kt) {
      const u16* Aq = selP + (long long)arow * Dd + kt + 16 * ss;
      rah[0] = *reinterpret_cast<const u16x8*>(Aq);
      rah[1] = *reinterpret_cast<const u16x8*>(Aq + 8);
      ral[0] = *reinterpret_cast<const u16x8*>(Aq + aPlane);
      ral[1] = *reinterpret_cast<const u16x8*>(Aq + aPlane + 8);
      const u16* Bq = Bn + (long long)brow * Dd + kt + 8 * sbc;
      rbh = *reinterpret_cast<const u16x8*>(Bq);
      rbl = *reinterpret_cast<const u16x8*>(Bq + bPlane);
    };
    load_tiles(0);
    for (int kt = 0; kt < Dd; kt += 32) {
      *reinterpret_cast<u16x8*>(&AsH[2 * ss][sr][0]) = rah[0];
      *reinterpret_cast<u16x8*>(&AsH[2 * ss + 1][sr][0]) = rah[1];
      *reinterpret_cast<u16x8*>(&AsL[2 * ss][sr][0]) = ral[0];
      *reinterpret_cast<u16x8*>(&AsL[2 * ss + 1][sr][0]) = ral[1];
      *reinterpret_cast<u16x8*>(&BsH[sbc][br][0]) = rbh;
      *reinterpret_cast<u16x8*>(&BsL[sbc][br][0]) = rbl;
      __syncthreads();
      if (kt + 32 < Dd) load_tiles(kt + 32);
      bf16x8 aH[4], aL[4];
#pragma unroll
      for (int fi = 0; fi < 4; ++fi) {
        aH[fi] = *reinterpret_cast<const bf16x8*>(&AsH[kg][wr + fi * 16 + r16][0]);
        aL[fi] = *reinterpret_cast<const bf16x8*>(&AsL[kg][wr + fi * 16 + r16][0]);
      }
#pragma unroll
      for (int fj = 0; fj < 2; ++fj) {
        const bf16x8 bH = *reinterpret_cast<const bf16x8*>(&BsH[kg][wc + fj * 16 + r16][0]);
        const bf16x8 bL = *reinterpret_cast<const bf16x8*>(&BsL[kg][wc + fj * 16 + r16][0]);
#pragma unroll
        for (int fi = 0; fi < 4; ++fi) {
          acc[fi][fj] = __builtin_amdgcn_mfma_f32_16x16x32_bf16(aH[fi], bH, acc[fi][fj], 0, 0, 0);
          acc[fi][fj] = __builtin_amdgcn_mfma_f32_16x16x32_bf16(aL[fi], bH, acc[fi][fj], 0, 0, 0);
          acc[fi][fj] = __builtin_amdgcn_mfma_f32_16x16x32_bf16(aH[fi], bL, acc[fi][fj], 0, 0, 0);
        }
      }
      __syncthreads();
    }
#pragma unroll
    for (int fi = 0; fi < 4; ++fi) {
#pragma unroll
      for (int rg = 0; rg < 4; ++rg) {
        const int r = by * 128 + wr + fi * 16 + kg * 4 + rg;
        const float ow = opw[(long long)r * 8 + n];
#pragma unroll
        for (int fj = 0; fj < 2; ++fj) {
          const float hv = acc[fi][fj][rg];
          float av;
          switch (n) {
            case 0: av = 0.5f * hv * (1.0f + erff(hv * 0.70710678118654752440f)); break;
            case 1: av = fmaxf(hv, 0.0f); break;
            case 2: { const float r_ = fmaxf(hv, 0.0f); av = r_ * r_; } break;
            case 3: av = hv / (1.0f + expf(-hv)); break;
            case 4: av = tanhf(hv); break;
            case 5: av = 1.0f / (1.0f + expf(-hv)); break;
            case 6: av = hv; break;
            default: av = -hv; break;
          }
          res[fi][fj][rg] += ow * av;
        }
      }
    }
  }
#pragma unroll
  for (int fi = 0; fi < 4; ++fi)
#pragma unroll
    for (int fj = 0; fj < 2; ++fj) {
      const int col = bx * 64 + wc + fj * 16 + r16;
#pragma unroll
      for (int rg = 0; rg < 4; ++rg) {
        const int r = by * 128 + wr + fi * 16 + kg * 4 + rg;
        part[(long long)r * Dd + col] = res[fi][fj][rg];
      }
    }
}

__global__ void decaypow_kernel(const float* __restrict__ decay_logit,
                                float* __restrict__ pw) {
  const int e = blockIdx.x * 256 + threadIdx.x;
  if (e < Tt) {
    const float decay = 1.0f / (1.0f + expf(-*decay_logit));
    pw[e] = powf(decay, (float)e);
  }
}

__global__ void rmsnorm_kernel(const float* __restrict__ x,
                               float* __restrict__ rstd) {
  const int t = blockIdx.x, tid = threadIdx.x;
  const float4* xr = reinterpret_cast<const float4*>(x + (long long)t * Vv);
  float s = 0.0f;
  for (int i = tid; i < Vv / 4; i += 256) {
    const float4 v = xr[i];
    s += v.x * v.x + v.y * v.y + v.z * v.z + v.w * v.w;
  }
  __shared__ float red[256];
  red[tid] = s;
  __syncthreads();
  for (int st = 128; st > 0; st >>= 1) {
    if (tid < st) red[tid] += red[tid + st];
    __syncthreads();
  }
  if (tid == 0) rstd[t] = rsqrtf(red[0] / (float)Vv + 1.1920929e-07f);
}

// split src f32 -> dst planes {hi[n], lo[n]}
__global__ void split_kernel(const float* __restrict__ src, u16* __restrict__ dst,
                             long long n) {
  const long long i0 = ((long long)blockIdx.x * 256 + threadIdx.x) * 4;
  const long long stride = (long long)gridDim.x * 1024;
  for (long long i = i0; i < n; i += stride) {
    const float4 v = *reinterpret_cast<const float4*>(src + i);
    u16 hh, ll; u16x4 hv, lv;
    split2(v.x, hh, ll); hv[0] = hh; lv[0] = ll;
    split2(v.y, hh, ll); hv[1] = hh; lv[1] = ll;
    split2(v.z, hh, ll); hv[2] = hh; lv[2] = ll;
    split2(v.w, hh, ll); hv[3] = hh; lv[3] = ll;
    *reinterpret_cast<u16x4*>(&dst[i]) = hv;
    *reinterpret_cast<u16x4*>(&dst[n + i]) = lv;
  }
}

// h = p0(h) + p1 + p2 + p3  (deterministic split-K combine)
__global__ void combine4_kernel(float* __restrict__ h, const float* __restrict__ p1,
                                const float* __restrict__ p2, const float* __restrict__ p3) {
  const long long total = (long long)NTOK * Dd;
  const long long i0 = ((long long)blockIdx.x * 256 + threadIdx.x) * 4;
  const long long stride = (long long)gridDim.x * 1024;
  for (long long i = i0; i < total; i += stride) {
    const float4 a = *reinterpret_cast<const float4*>(h + i);
    const float4 b = *reinterpret_cast<const float4*>(p1 + i);
    const float4 c = *reinterpret_cast<const float4*>(p2 + i);
    const float4 d = *reinterpret_cast<const float4*>(p3 + i);
    float4 o;
    o.x = a.x + b.x + c.x + d.x;
    o.y = a.y + b.y + c.y + d.y;
    o.z = a.z + b.z + c.z + d.z;
    o.w = a.w + b.w + c.w + d.w;
    *reinterpret_cast<float4*>(h + i) = o;
  }
}

// per-token: read_w softmax -> selP planes; op_w softmax; write_w sigmoid in place
__global__ void policy_kernel(float* __restrict__ pol, const float* __restrict__ h,
                              u16* __restrict__ selP, float* __restrict__ opw) {
  const int t = blockIdx.x, tid = threadIdx.x;
  float* prow = pol + (long long)t * PO;
  __shared__ float red[256];
  const float v0 = prow[tid], v1 = prow[tid + 256];
  red[tid] = fmaxf(v0, v1);
  __syncthreads();
  for (int s = 128; s > 0; s >>= 1) {
    if (tid < s) red[tid] = fmaxf(red[tid], red[tid + s]);
    __syncthreads();
  }
  const float mx = red[0];
  __syncthreads();
  const float e0 = expf(v0 - mx), e1 = expf(v1 - mx);
  red[tid] = e0 + e1;
  __syncthreads();
  for (int s = 128; s > 0; s >>= 1) {
    if (tid < s) red[tid] += red[tid + s];
    __syncthreads();
  }
  const float inv = 1.0f / red[0];
  const float* hrow = h + (long long)t * Dd;
  u16 hh, ll;
  const float s0 = hrow[tid] * e0 * inv;
  split2(s0, hh, ll);
  selP[(long long)t * Dd + tid] = hh;
  selP[(long long)t * Dd + tid + 4194304] = ll;
  const float s1 = hrow[tid + 256] * e1 * inv;
  split2(s1, hh, ll);
  selP[(long long)t * Dd + tid + 256] = hh;
  selP[(long long)t * Dd + tid + 256 + 4194304] = ll;
  if (tid == 0) {
    float ov[8];
    float om = -1e30f;
    for (int n = 0; n < 8; ++n) { ov[n] = prow[512 + n]; om = fmaxf(om, ov[n]); }
    float osum = 0.0f;
    for (int n = 0; n < 8; ++n) { ov[n] = expf(ov[n] - om); osum += ov[n]; }
    const float oi = 1.0f / osum;
    for (int n = 0; n < 8; ++n) opw[(long long)t * 8 + n] = ov[n] * oi;
  }
  const float w0 = prow[520 + tid];
  prow[520 + tid] = 1.0f / (1.0f + expf(-w0));
  const float w1 = prow[520 + 256 + tid];
  prow[520 + 256 + tid] = 1.0f / (1.0f + expf(-w1));
}

// result planes = write_w * (p0 + p1)
__global__ void combine_kernel(const float* __restrict__ p0, const float* __restrict__ p1,
                               const float* __restrict__ pol, u16* __restrict__ resP) {
  const long long total = (long long)NTOK * Dd;
  const long long i0 = ((long long)blockIdx.x * 256 + threadIdx.x) * 4;
  const long long stride = (long long)gridDim.x * 1024;
  for (long long i = i0; i < total; i += stride) {
    const float4 a = *reinterpret_cast<const float4*>(p0 + i);
    const float4 b = *reinterpret_cast<const float4*>(p1 + i);
    const long long t = i >> 9;
    const int e = (int)(i & 511);
    const float4 wv = *reinterpret_cast<const float4*>(pol + t * PO + 520 + e);
    u16 hh, ll; u16x4 hv, lv;
    split2((a.x + b.x) * wv.x, hh, ll); hv[0] = hh; lv[0] = ll;
    split2((a.y + b.y) * wv.y, hh, ll); hv[1] = hh; lv[1] = ll;
    split2((a.z + b.z) * wv.z, hh, ll); hv[2] = hh; lv[2] = ll;
    split2((a.w + b.w) * wv.w, hh, ll); hv[3] = hh; lv[3] = ll;
    *reinterpret_cast<u16x4*>(&resP[i]) = hv;
    *reinterpret_cast<u16x4*>(&resP[i + 4194304]) = lv;
  }
}

} // namespace

extern "C" void kernel_launch(void* const* d_in, const int* in_sizes, int n_in,
                              void* d_out, int out_size, void* d_ws, size_t ws_size,
                              hipStream_t stream) {
  const float* x    = (const float*)d_in[0];
  const float* Wc   = (const float*)d_in[1];
  const float* We   = (const float*)d_in[2];
  const float* Wq   = (const float*)d_in[3];
  const float* Wk   = (const float*)d_in[4];
  const float* Wv   = (const float*)d_in[5];
  const float* W1   = (const float*)d_in[6];
  const float* b1   = (const float*)d_in[7];
  const float* W2   = (const float*)d_in[8];
  const float* b2   = (const float*)d_in[9];
  const float* Wops = (const float*)d_in[10];
  const float* dlg  = (const float*)d_in[11];
  const float* msc  = (const float*)d_in[12];
  const float* asc  = (const float*)d_in[13];

  float* ws = (float*)d_ws;
  // ---- lifetime-aliased layout, same 134.8 MB envelope ----
  float* h    = ws;                           // [0, 4.19M) f32; splitK p0; later p0(opbank)
  u16*   qkP  = (u16*)(ws + 4194304);         // splitK p1/p2 early; q/k planes; selP; WeP
  u16*   vTP  = (u16*)(ws + 12582912);        // splitK p3 early; vT planes; W2P; p1(opbank)
  u16*   scP  = (u16*)(ws + 16777216);        // WcP early; scores planes; a1P/WopsP later
  float* pol  = ws + 25165824;                // 8,454,144 f32 (early: W1P)
  float* rstd = ws + 33619968;                // 8192
  float* dpw  = rstd + 8192;                  // 2048
  float* opw  = dpw + 2048;                   // 65,536
  float* out  = (float*)d_out;

  u16*   WcP   = scP;                         // dead after h GEMM
  u16*   WqP   = (u16*)(ws + 20971520);       // Wq/Wk/Wv packs (524,288 u16 apart)
  u16*   W1P   = (u16*)(ws + 25165824);       // pol region; overwritten by W2 GEMM
  u16*   W2P   = (u16*)(ws + 12582912);       // vT region (vT dead after mem)
  u16*   WopsP = (u16*)(ws + 16777216);       // scores region (a1 dead after W2)
  u16*   a1P   = (u16*)(ws + 16777216);       // after mem, until W2
  u16*   selP  = qkP;                         // after policy (q dead)
  u16*   resP  = (u16*)(ws + 8388608);        // k region (k dead after scores)
  u16*   WeP   = qkP;                         // after opbank (sel dead)
  float* ob0   = h;                           // opbank partial 0 (h dead after policy)
  float* ob1   = ws + 12582912;               // opbank partial 1
  float* sk1   = ws + 4194304;                // splitK partials (pre-qk regions)
  float* sk2   = ws + 8388608;
  float* sk3   = ws + 12582912;

  decaypow_kernel<<<8, 256, 0, stream>>>(dlg, dpw);
  rmsnorm_kernel<<<NTOK, 256, 0, stream>>>(x, rstd);
  split_kernel<<<2048, 256, 0, stream>>>(Wc, WcP, 4194304LL);
  split_kernel<<<256, 256, 0, stream>>>(Wq, WqP, 262144LL);
  split_kernel<<<256, 256, 0, stream>>>(Wk, WqP + 524288, 262144LL);
  split_kernel<<<256, 256, 0, stream>>>(Wv, WqP + 1048576, 262144LL);

  // h = (x*rstd) @ Wc^T  [8192 x 512 x 8192], split-K x4 (bz = K-chunk)
  gemm_mfma<EPI_STORE_F32, true, true, false, false><<<dim3(512, 1, 4), 256, 0, stream>>>(
      8, Dd, 2048, x, Vv, 2048, 0, WcP, Vv, 2048, 4194304, h, Dd, 4194304, 0,
      rstd, nullptr, nullptr, nullptr);
  combine4_kernel<<<2048, 256, 0, stream>>>(h, sk1, sk2, sk3);
  // q,k = h @ W{q,k}^T  fused over z  [8192 x 512 x 512]
  gemm_mfma<EPI_STORE_P, true, false, false, false><<<dim3(512, 1, 2), 256, 0, stream>>>(
      8, Dd, Dd, h, Dd, 0, 0, WqP, Dd, 524288, 262144, qkP, Dd, 8388608, 4194304,
      nullptr, nullptr, nullptr, nullptr);
  // vT[b][d][t] = (h @ Wv^T)^T
  gemm_mfma<EPI_VT_P, true, false, false, false><<<dim3(512, 1, 1), 256, 0, stream>>>(
      8, Dd, Dd, h, Dd, 0, 0, WqP + 1048576, Dd, 0, 262144, vTP, 0, 0, 4194304,
      nullptr, nullptr, nullptr, nullptr);
  // scores = (q @ k^T) * w  [per batch 2048 x 2048 x 512], lower-tri tiles skipped
  gemm_mfma<EPI_DECAY_P, false, false, false, false><<<dim3(512, 1, 4), 256, 0, stream>>>(
      32, Tt, Dd, qkP, Dd, 1048576, 4194304, qkP + 8388608, Dd, 1048576, 4194304,
      scP, Tt, 4194304, 16777216, nullptr, nullptr, nullptr, dpw);
  // h += mem_scale * (scores @ v)  [per batch 2048 x 512 x 2048], zero k skipped
  gemm_mfma<EPI_ACCUM, false, false, true, false><<<dim3(128, 1, 4), 256, 0, stream>>>(
      8, Dd, Tt, scP, Tt, 4194304, 16777216, vTP, Tt, 1048576, 4194304,
      h, Dd, 1048576, 0, nullptr, nullptr, msc, nullptr);
  split_kernel<<<512, 256, 0, stream>>>(W1, W1P, 524288LL);
  // a1 = gelu(h @ W1^T + b1)  [8192 x 1024 x 512]
  gemm_mfma<EPI_GELU_P, true, false, false, false><<<dim3(1024, 1, 1), 256, 0, stream>>>(
      16, HID, Dd, h, Dd, 0, 0, W1P, Dd, 0, 524288, a1P, HID, 0, 8388608,
      nullptr, b1, nullptr, nullptr);
  split_kernel<<<1024, 256, 0, stream>>>(W2, W2P, 1056768LL);
  // pol = a1 @ W2^T + b2  [8192 x 1032 x 1024]
  gemm_mfma<EPI_BIAS_F32, false, false, false, true><<<dim3(1088, 1, 1), 256, 0, stream>>>(
      17, PO, HID, a1P, HID, 0, 8388608, W2P, HID, 0, 1056768, pol, PO, 0, 0,
      nullptr, b2, nullptr, nullptr);
  policy_kernel<<<NTOK, 256, 0, stream>>>(pol, h, selP, opw);
  split_kernel<<<2048, 256, 0, stream>>>(Wops, WopsP, 2097152LL);
  // opbank partials: z=0 -> ops 0..3 into ob0, z=1 -> ops 4..7 into ob1
  opbank_mfma<<<dim3(512, 1, 2), 256, 0, stream>>>(
      8, selP, 4194304, WopsP, 2097152, opw, ob0, ob1);
  split_kernel<<<2048, 256, 0, stream>>>(We, WeP, 4194304LL);
  combine_kernel<<<2048, 256, 0, stream>>>(ob0, ob1, pol, resP);
  // out = (result @ We^T) * act_scale  [8192 x 8192 x 512]
  gemm_mfma<EPI_OUT, false, false, false, false><<<dim3(8192, 1, 1), 256, 0, stream>>>(
      128, Vv, Dd, resP, Dd, 0, 4194304, WeP, Dd, 0, 4194304, out, Vv, 0, 0,
      nullptr, nullptr, asc, nullptr);
}